// Round 1
// baseline (1427.663 us; speedup 1.0000x reference)
//
#include <hip/hip_runtime.h>
#include <math.h>

#define BB 2
#define SS 2048
#define DD 64
#define HH 12
#define NEGV -99999.0f

// ---------------------------------------------------------------------------
// Kernel 1: fused QKV projection.
// x:[B*S,64] @ W[64,768] + b -> stored as [B,H,S,64] in ws.
// grid (256 row-tiles, 9 col-groups), block 256. Each col-group is 256 cols of
// one of {Wq,Wk,Wv} (768 = 3*256, so a group never straddles matrices).
// ---------------------------------------------------------------------------
__global__ __launch_bounds__(256) void qkv_kernel(
    const float* __restrict__ x,
    const float* __restrict__ Wq, const float* __restrict__ bq,
    const float* __restrict__ Wk, const float* __restrict__ bk,
    const float* __restrict__ Wv, const float* __restrict__ bv,
    float* __restrict__ Q, float* __restrict__ K, float* __restrict__ V)
{
    __shared__ float xs[16 * 64];
    const int rBase = blockIdx.x * 16;
    const int cg    = blockIdx.y;          // 0..8
    const int mat   = cg / 3;              // 0=q 1=k 2=v
    const int col   = (cg % 3) * 256 + threadIdx.x;   // 0..767

    const float* W    = (mat == 0) ? Wq : (mat == 1) ? Wk : Wv;
    const float* bias = (mat == 0) ? bq : (mat == 1) ? bk : bv;
    float*       Out  = (mat == 0) ? Q  : (mat == 1) ? K  : V;

    for (int i = threadIdx.x; i < 16 * 64; i += 256)
        xs[i] = x[rBase * 64 + i];
    __syncthreads();

    float acc[16];
#pragma unroll
    for (int r = 0; r < 16; r++) acc[r] = 0.f;

    for (int k = 0; k < 64; k++) {
        float w = W[k * 768 + col];
#pragma unroll
        for (int r = 0; r < 16; r++) acc[r] += xs[r * 64 + k] * w;
    }

    const float bb = bias[col];
    const int h = col >> 6, d = col & 63;
#pragma unroll
    for (int r = 0; r < 16; r++) {
        int row = rBase + r;
        int b = row >> 11, s = row & 2047;
        Out[(((size_t)b * HH + h) * SS + s) * 64 + d] = acc[r] + bb;
    }
}

// ---------------------------------------------------------------------------
// Kernel 2: flash-style attention with the quirky tril/zero mask.
// Block = 256 threads (4 waves); each wave owns 4 query rows (16 rows/block).
// Iterates K/V tiles of 64 keys staged in LDS; online softmax per row.
// grid (S/16, B*H).
// ---------------------------------------------------------------------------
__global__ __launch_bounds__(256) void attn_kernel(
    const float* __restrict__ Q, const float* __restrict__ Kg,
    const float* __restrict__ Vg, float* __restrict__ Og)
{
    __shared__ float Kt[64 * 65];   // padded: bank = (lane + d) % 32 -> 2-way (free)
    __shared__ float Vt[64 * 64];   // bank = lane % 32 -> 2-way (free)
    __shared__ float Qs[16 * 64];

    const int bh    = blockIdx.y;
    const int qBase = blockIdx.x * 16;
    const int wave  = threadIdx.x >> 6;
    const int lane  = threadIdx.x & 63;

    const float* Qp = Q  + ((size_t)bh * SS + qBase) * 64;
    const float* Kp = Kg + (size_t)bh * SS * 64;
    const float* Vp = Vg + (size_t)bh * SS * 64;

    for (int i = threadIdx.x; i < 16 * 64; i += 256)
        Qs[i] = Qp[i];

    float m[4], l[4], o[4];
#pragma unroll
    for (int r = 0; r < 4; r++) { m[r] = -INFINITY; l[r] = 0.f; o[r] = 0.f; }

    const int q0 = qBase + wave * 4;   // this wave's first query row

    // kt <= qBase suffices: qBase % 16 == 0, so the 64-wide chunk at
    // kt == qBase already covers keys up to qBase+63 >= qBase+15.
    for (int kt = 0; kt <= qBase; kt += 64) {
        __syncthreads();
        for (int i = threadIdx.x; i < 64 * 64; i += 256) {
            int rr = i >> 6, cc = i & 63;
            Kt[rr * 65 + cc] = Kp[(size_t)kt * 64 + i];
            Vt[i]            = Vp[(size_t)kt * 64 + i];
        }
        __syncthreads();

        const int key = kt + lane;   // lane j computes scores for key kt+j
        float s[4];
#pragma unroll
        for (int r = 0; r < 4; r++) s[r] = 0.f;

        for (int d = 0; d < 64; d++) {
            float kv = Kt[lane * 65 + d];
#pragma unroll
            for (int r = 0; r < 4; r++)
                s[r] += Qs[(wave * 4 + r) * 64 + d] * kv;  // Qs read = broadcast
        }

#pragma unroll
        for (int r = 0; r < 4; r++) {
            const int qrow = q0 + r;
            float sv = s[r];
            // faithful mask: strictly-upper -> NEG; exact-zero in tril -> NEG
            sv = (key <= qrow) ? ((sv != 0.f) ? sv : NEGV) : NEGV;

            float cm = sv;
            for (int off = 32; off; off >>= 1)
                cm = fmaxf(cm, __shfl_xor(cm, off));
            const float mn = fmaxf(m[r], cm);
            const float p  = expf(sv - mn);     // masked -> exp(~-1e5) = 0
            float ps = p;
            for (int off = 32; off; off >>= 1)
                ps += __shfl_xor(ps, off);
            const float alpha = expf(m[r] - mn);
            l[r] = l[r] * alpha + ps;
            m[r] = mn;
            o[r] *= alpha;
            // o_d += sum_j p_j * V[j][d]; p_j broadcast via shfl (no barrier)
            for (int j = 0; j < 64; j++)
                o[r] += __shfl(p, j) * Vt[j * 64 + lane];
        }
    }

#pragma unroll
    for (int r = 0; r < 4; r++)
        Og[((size_t)bh * SS + q0 + r) * 64 + lane] = o[r] / l[r];
}

// ---------------------------------------------------------------------------
// Kernel 3: output projection. O:[B,H,S,64] gathered per (b,s) row ->
// [768] @ Wo[768,64] + bo. Block = 256 threads = 4 rows x 64 cols.
// ---------------------------------------------------------------------------
__global__ __launch_bounds__(256) void out_kernel(
    const float* __restrict__ Og, const float* __restrict__ Wo,
    const float* __restrict__ bo, float* __restrict__ out)
{
    __shared__ float os[4 * 772];   // pad 768->772: avoid 4-way same-bank
    const int rBase = blockIdx.x * 4;
    const int rl = threadIdx.x >> 6, c = threadIdx.x & 63;

    for (int i = threadIdx.x; i < 4 * 768; i += 256) {
        int r = i / 768, col = i % 768;
        int row = rBase + r;
        int b = row >> 11, s = row & 2047;
        int h = col >> 6, d = col & 63;
        os[r * 772 + col] = Og[(((size_t)b * HH + h) * SS + s) * 64 + d];
    }
    __syncthreads();

    float acc = 0.f;
    for (int k = 0; k < 768; k++)
        acc += os[rl * 772 + k] * Wo[k * 64 + c];

    out[(size_t)(rBase + rl) * 64 + c] = acc + bo[c];
}

// ---------------------------------------------------------------------------
extern "C" void kernel_launch(void* const* d_in, const int* in_sizes, int n_in,
                              void* d_out, int out_size, void* d_ws, size_t ws_size,
                              hipStream_t stream)
{
    const float* x  = (const float*)d_in[0];
    const float* Wq = (const float*)d_in[1];
    const float* bq = (const float*)d_in[2];
    const float* Wk = (const float*)d_in[3];
    const float* bk = (const float*)d_in[4];
    const float* Wv = (const float*)d_in[5];
    const float* bv = (const float*)d_in[6];
    const float* Wo = (const float*)d_in[7];
    const float* bo = (const float*)d_in[8];
    float* out = (float*)d_out;

    float* ws = (float*)d_ws;
    const size_t QSZ = (size_t)BB * HH * SS * DD;   // 3,145,728 floats
    float* Q = ws;
    float* K = ws + QSZ;
    float* V = ws + 2 * QSZ;
    float* O = ws + 3 * QSZ;

    qkv_kernel<<<dim3(256, 9), 256, 0, stream>>>(x, Wq, bq, Wk, bk, Wv, bv, Q, K, V);
    attn_kernel<<<dim3(SS / 16, BB * HH), 256, 0, stream>>>(Q, K, V, O);
    out_kernel<<<(BB * SS) / 4, 256, 0, stream>>>(O, Wo, bo, out);
}

// Round 2
// 257.062 us; speedup vs baseline: 5.5538x; 5.5538x over previous
//
#include <hip/hip_runtime.h>
#include <math.h>

#define BB 2
#define SS 2048
#define DD 64
#define HH 12
#define NEGV -99999.0f

typedef _Float16 v8h __attribute__((ext_vector_type(8)));
typedef _Float16 v4h __attribute__((ext_vector_type(4)));
typedef _Float16 v2h __attribute__((ext_vector_type(2)));
typedef float    v4f __attribute__((ext_vector_type(4)));

// ---------------------------------------------------------------------------
// Kernel 1: fused QKV projection (unchanged from R1; ~small).
// ---------------------------------------------------------------------------
__global__ __launch_bounds__(256) void qkv_kernel(
    const float* __restrict__ x,
    const float* __restrict__ Wq, const float* __restrict__ bq,
    const float* __restrict__ Wk, const float* __restrict__ bk,
    const float* __restrict__ Wv, const float* __restrict__ bv,
    float* __restrict__ Q, float* __restrict__ K, float* __restrict__ V)
{
    __shared__ float xs[16 * 64];
    const int rBase = blockIdx.x * 16;
    const int cg    = blockIdx.y;
    const int mat   = cg / 3;
    const int col   = (cg % 3) * 256 + threadIdx.x;

    const float* W    = (mat == 0) ? Wq : (mat == 1) ? Wk : Wv;
    const float* bias = (mat == 0) ? bq : (mat == 1) ? bk : bv;
    float*       Out  = (mat == 0) ? Q  : (mat == 1) ? K  : V;

    for (int i = threadIdx.x; i < 16 * 64; i += 256)
        xs[i] = x[rBase * 64 + i];
    __syncthreads();

    float acc[16];
#pragma unroll
    for (int r = 0; r < 16; r++) acc[r] = 0.f;

    for (int k = 0; k < 64; k++) {
        float w = W[k * 768 + col];
#pragma unroll
        for (int r = 0; r < 16; r++) acc[r] += xs[r * 64 + k] * w;
    }

    const float bb = bias[col];
    const int h = col >> 6, d = col & 63;
#pragma unroll
    for (int r = 0; r < 16; r++) {
        int row = rBase + r;
        int b = row >> 11, s = row & 2047;
        Out[(((size_t)b * HH + h) * SS + s) * 64 + d] = acc[r] + bb;
    }
}

// ---------------------------------------------------------------------------
// Kernel 2: MFMA flash attention (fp16 mfma_f32_16x16x32_f16).
// Block = 4 waves x 16 q-rows = 64 q rows. K-tiles of 64 keys in LDS.
// Layouts (verified m89/m120): A[m=lane&15][k=(lane>>4)*8+j];
// C/D: col=lane&15, row=(lane>>4)*4+reg.
// ---------------------------------------------------------------------------
__global__ __launch_bounds__(256) void attn_mfma_kernel(
    const float* __restrict__ Q, const float* __restrict__ Kg,
    const float* __restrict__ Vg, float* __restrict__ Og)
{
    __shared__ _Float16 Klds[64][72];      // [key][d], pad 72: width-floor access
    __shared__ _Float16 Vt[64][72];        // [d][key] (transposed for PV B-frag)
    __shared__ _Float16 Plds[4][16][72];   // per-wave P tile, C->A layout bridge

    const int bh    = blockIdx.y;
    const int qtile = gridDim.x - 1 - blockIdx.x;   // long blocks first
    const int qBase = qtile * 64;
    const int wave  = threadIdx.x >> 6;
    const int lane  = threadIdx.x & 63;
    const int llow  = lane & 15;
    const int quad  = lane >> 4;
    const int q0    = qBase + wave * 16;            // wave's first q row

    const float* Qp = Q  + ((size_t)bh * SS + q0) * 64;
    const float* Kp = Kg + (size_t)bh * SS * 64;
    const float* Vp = Vg + (size_t)bh * SS * 64;

    // Q A-fragments: chunk c covers d = 32c + quad*8 + j
    v8h qa[2];
#pragma unroll
    for (int c = 0; c < 2; c++) {
        const float* src = Qp + llow * 64 + 32 * c + quad * 8;
        float4 f0 = *(const float4*)(src);
        float4 f1 = *(const float4*)(src + 4);
        qa[c][0] = (_Float16)f0.x; qa[c][1] = (_Float16)f0.y;
        qa[c][2] = (_Float16)f0.z; qa[c][3] = (_Float16)f0.w;
        qa[c][4] = (_Float16)f1.x; qa[c][5] = (_Float16)f1.y;
        qa[c][6] = (_Float16)f1.z; qa[c][7] = (_Float16)f1.w;
    }

    v4f o[4];
    float m[4], l[4];
#pragma unroll
    for (int nb = 0; nb < 4; nb++) o[nb] = (v4f){0.f, 0.f, 0.f, 0.f};
#pragma unroll
    for (int r = 0; r < 4; r++) { m[r] = -INFINITY; l[r] = 0.f; }

    for (int kt = 0; kt <= qBase; kt += 64) {
        __syncthreads();
        // ---- stage K tile: [key][d] fp32 -> fp16, b64 writes ----
#pragma unroll
        for (int rep = 0; rep < 4; rep++) {
            int u   = threadIdx.x + 256 * rep;     // 0..1023
            int key = u >> 4, c4 = u & 15;
            float4 f = *(const float4*)(Kp + (size_t)(kt + key) * 64 + 4 * c4);
            v4h h; h[0] = (_Float16)f.x; h[1] = (_Float16)f.y;
                   h[2] = (_Float16)f.z; h[3] = (_Float16)f.w;
            *(v4h*)&Klds[key][4 * c4] = h;
        }
        // ---- stage V transposed: Vt[d][key], paired keys -> b32 writes ----
#pragma unroll
        for (int rep = 0; rep < 2; rep++) {
            int u  = threadIdx.x + 256 * rep;      // 0..511
            int kp = u & 31, c4 = u >> 5;          // keys 2kp,2kp+1; d 4c4..4c4+3
            const float* base = Vp + (size_t)(kt + 2 * kp) * 64 + 4 * c4;
            float4 f0 = *(const float4*)(base);
            float4 f1 = *(const float4*)(base + 64);
            v2h p;
            p[0] = (_Float16)f0.x; p[1] = (_Float16)f1.x; *(v2h*)&Vt[4*c4+0][2*kp] = p;
            p[0] = (_Float16)f0.y; p[1] = (_Float16)f1.y; *(v2h*)&Vt[4*c4+1][2*kp] = p;
            p[0] = (_Float16)f0.z; p[1] = (_Float16)f1.z; *(v2h*)&Vt[4*c4+2][2*kp] = p;
            p[0] = (_Float16)f0.w; p[1] = (_Float16)f1.w; *(v2h*)&Vt[4*c4+3][2*kp] = p;
        }
        __syncthreads();

        // ---- QK^T: S[16q x 64keys] as 4 col-blocks of 16 ----
        v4f s[4];
#pragma unroll
        for (int cb = 0; cb < 4; cb++) {
            v4f acc = (v4f){0.f, 0.f, 0.f, 0.f};
            const _Float16* kb = &Klds[16 * cb + llow][quad * 8];
            acc = __builtin_amdgcn_mfma_f32_16x16x32_f16(qa[0], *(const v8h*)kb,        acc, 0, 0, 0);
            acc = __builtin_amdgcn_mfma_f32_16x16x32_f16(qa[1], *(const v8h*)(kb + 32), acc, 0, 0, 0);
            s[cb] = acc;
        }

        // ---- faithful mask: strictly-upper OR exact-zero -> NEG ----
#pragma unroll
        for (int cb = 0; cb < 4; cb++) {
            const int key = kt + 16 * cb + llow;
#pragma unroll
            for (int r = 0; r < 4; r++) {
                const int row = q0 + quad * 4 + r;
                float sv = s[cb][r];
                s[cb][r] = (key <= row && sv != 0.f) ? sv : NEGV;
            }
        }

        // ---- online softmax (per row; rows live in 16-lane quads) ----
        float tm[4], rs[4];
#pragma unroll
        for (int r = 0; r < 4; r++) {
            tm[r] = fmaxf(fmaxf(s[0][r], s[1][r]), fmaxf(s[2][r], s[3][r]));
            tm[r] = fmaxf(tm[r], __shfl_xor(tm[r], 1));
            tm[r] = fmaxf(tm[r], __shfl_xor(tm[r], 2));
            tm[r] = fmaxf(tm[r], __shfl_xor(tm[r], 4));
            tm[r] = fmaxf(tm[r], __shfl_xor(tm[r], 8));
        }
        float alpha[4];
#pragma unroll
        for (int r = 0; r < 4; r++) {
            const float mn = fmaxf(m[r], tm[r]);
            alpha[r] = __expf(m[r] - mn);
            m[r] = mn;
            rs[r] = 0.f;
        }
#pragma unroll
        for (int cb = 0; cb < 4; cb++)
#pragma unroll
            for (int r = 0; r < 4; r++) {
                const float p = __expf(s[cb][r] - m[r]);   // masked -> 0
                s[cb][r] = p;
                rs[r] += p;
            }
#pragma unroll
        for (int r = 0; r < 4; r++) {
            rs[r] += __shfl_xor(rs[r], 1);
            rs[r] += __shfl_xor(rs[r], 2);
            rs[r] += __shfl_xor(rs[r], 4);
            rs[r] += __shfl_xor(rs[r], 8);
            l[r] = l[r] * alpha[r] + rs[r];
#pragma unroll
            for (int nb = 0; nb < 4; nb++) o[nb][r] *= alpha[r];
        }

        // ---- P: C-layout -> LDS -> A-layout (per-wave tile, no barrier) ----
#pragma unroll
        for (int cb = 0; cb < 4; cb++)
#pragma unroll
            for (int r = 0; r < 4; r++)
                Plds[wave][quad * 4 + r][16 * cb + llow] = (_Float16)s[cb][r];

        v8h pa[2];
#pragma unroll
        for (int c = 0; c < 2; c++)
            pa[c] = *(const v8h*)&Plds[wave][llow][32 * c + quad * 8];

        // ---- PV: O[16q x 64d] += P @ V ----
#pragma unroll
        for (int nb = 0; nb < 4; nb++) {
            const _Float16* vb = &Vt[16 * nb + llow][quad * 8];
            o[nb] = __builtin_amdgcn_mfma_f32_16x16x32_f16(pa[0], *(const v8h*)vb,        o[nb], 0, 0, 0);
            o[nb] = __builtin_amdgcn_mfma_f32_16x16x32_f16(pa[1], *(const v8h*)(vb + 32), o[nb], 0, 0, 0);
        }
    }

    // ---- epilogue: O / l ----
    float* op = Og + ((size_t)bh * SS + q0) * 64;
#pragma unroll
    for (int nb = 0; nb < 4; nb++)
#pragma unroll
        for (int r = 0; r < 4; r++)
            op[(quad * 4 + r) * 64 + 16 * nb + llow] = o[nb][r] / l[r];
}

// ---------------------------------------------------------------------------
// Kernel 3: output projection (unchanged from R1).
// ---------------------------------------------------------------------------
__global__ __launch_bounds__(256) void out_kernel(
    const float* __restrict__ Og, const float* __restrict__ Wo,
    const float* __restrict__ bo, float* __restrict__ out)
{
    __shared__ float os[4 * 772];
    const int rBase = blockIdx.x * 4;
    const int rl = threadIdx.x >> 6, c = threadIdx.x & 63;

    for (int i = threadIdx.x; i < 4 * 768; i += 256) {
        int r = i / 768, col = i % 768;
        int row = rBase + r;
        int b = row >> 11, s = row & 2047;
        int h = col >> 6, d = col & 63;
        os[r * 772 + col] = Og[(((size_t)b * HH + h) * SS + s) * 64 + d];
    }
    __syncthreads();

    float acc = 0.f;
    for (int k = 0; k < 768; k++)
        acc += os[rl * 772 + k] * Wo[k * 64 + c];

    out[(size_t)(rBase + rl) * 64 + c] = acc + bo[c];
}

// ---------------------------------------------------------------------------
extern "C" void kernel_launch(void* const* d_in, const int* in_sizes, int n_in,
                              void* d_out, int out_size, void* d_ws, size_t ws_size,
                              hipStream_t stream)
{
    const float* x  = (const float*)d_in[0];
    const float* Wq = (const float*)d_in[1];
    const float* bq = (const float*)d_in[2];
    const float* Wk = (const float*)d_in[3];
    const float* bk = (const float*)d_in[4];
    const float* Wv = (const float*)d_in[5];
    const float* bv = (const float*)d_in[6];
    const float* Wo = (const float*)d_in[7];
    const float* bo = (const float*)d_in[8];
    float* out = (float*)d_out;

    float* ws = (float*)d_ws;
    const size_t QSZ = (size_t)BB * HH * SS * DD;
    float* Q = ws;
    float* K = ws + QSZ;
    float* V = ws + 2 * QSZ;
    float* O = ws + 3 * QSZ;

    qkv_kernel<<<dim3(256, 9), 256, 0, stream>>>(x, Wq, bq, Wk, bk, Wv, bv, Q, K, V);
    attn_mfma_kernel<<<dim3(SS / 64, BB * HH), 256, 0, stream>>>(Q, K, V, O);
    out_kernel<<<(BB * SS) / 4, 256, 0, stream>>>(O, Wo, bo, out);
}

// Round 3
// 165.532 us; speedup vs baseline: 8.6247x; 1.5529x over previous
//
#include <hip/hip_runtime.h>
#include <math.h>

#define BB 2
#define SS 2048
#define DD 64
#define HH 12
#define NEGV -99999.0f
#define CFIX 16.0f

typedef _Float16 v8h __attribute__((ext_vector_type(8)));
typedef short    v8s __attribute__((ext_vector_type(8)));
typedef short    v4s __attribute__((ext_vector_type(4)));
typedef float    v4f __attribute__((ext_vector_type(4)));

__device__ __forceinline__ unsigned short f2bf(float f) {
    unsigned u = __float_as_uint(f);
    u += 0x7FFF + ((u >> 16) & 1);          // RTN-even
    return (unsigned short)(u >> 16);
}

__device__ __forceinline__ void async16(const void* g, void* l) {
    __builtin_amdgcn_global_load_lds(
        (const __attribute__((address_space(1))) unsigned int*)g,
        (__attribute__((address_space(3))) unsigned int*)l, 16, 0, 0);
}

// ---------------------------------------------------------------------------
// Kernel 1: fused QKV projection. fp32 math (unchanged), outputs:
// Q16,K16 fp16 [bh][s][64]; VT bf16 [bh][d][s] (transposed for PV B-frags).
// ---------------------------------------------------------------------------
__global__ __launch_bounds__(256) void qkv_kernel(
    const float* __restrict__ x,
    const float* __restrict__ Wq, const float* __restrict__ bq,
    const float* __restrict__ Wk, const float* __restrict__ bk,
    const float* __restrict__ Wv, const float* __restrict__ bv,
    _Float16* __restrict__ Q16, _Float16* __restrict__ K16,
    unsigned short* __restrict__ VT)
{
    __shared__ float xs[16 * 64];
    const int rBase = blockIdx.x * 16;
    const int cg    = blockIdx.y;
    const int mat   = cg / 3;
    const int col   = (cg % 3) * 256 + threadIdx.x;

    const float* W    = (mat == 0) ? Wq : (mat == 1) ? Wk : Wv;
    const float* bias = (mat == 0) ? bq : (mat == 1) ? bk : bv;

    for (int i = threadIdx.x; i < 16 * 64; i += 256)
        xs[i] = x[rBase * 64 + i];
    __syncthreads();

    float acc[16];
#pragma unroll
    for (int r = 0; r < 16; r++) acc[r] = 0.f;

    for (int k = 0; k < 64; k++) {
        float w = W[k * 768 + col];
#pragma unroll
        for (int r = 0; r < 16; r++) acc[r] += xs[r * 64 + k] * w;
    }

    const float bb = bias[col];
    const int h = col >> 6, d = col & 63;

    if (mat < 2) {
        _Float16* Out = (mat == 0) ? Q16 : K16;
#pragma unroll
        for (int r = 0; r < 16; r++) {
            int row = rBase + r;
            int b = row >> 11, s = row & 2047;
            Out[(((size_t)b * HH + h) * SS + s) * 64 + d] = (_Float16)(acc[r] + bb);
        }
    } else {
        const int b = rBase >> 11, s0 = rBase & 2047;   // 16 | 2048: no straddle
        unsigned short tmp[16];
#pragma unroll
        for (int r = 0; r < 16; r++) tmp[r] = f2bf(acc[r] + bb);
        size_t base = ((size_t)(b * HH + h) * 64 + d) * SS + s0;
        v8s w0, w1;
#pragma unroll
        for (int r = 0; r < 8; r++) { w0[r] = (short)tmp[r]; w1[r] = (short)tmp[r + 8]; }
        *(v8s*)&VT[base]     = w0;
        *(v8s*)&VT[base + 8] = w1;
    }
}

// ---------------------------------------------------------------------------
// Kernel 2: MFMA flash attention, fixed-C softmax, async dbuf staging.
// Block = 4 waves x 16 q rows. XOR-swizzled K/V LDS (global_load_lds).
// ---------------------------------------------------------------------------
__global__ __launch_bounds__(256) void attn_kernel(
    const _Float16* __restrict__ Q16, const _Float16* __restrict__ K16,
    const unsigned short* __restrict__ VTg, _Float16* __restrict__ O16)
{
    __shared__ __align__(16) _Float16       Kl[2][64 * 64];
    __shared__ __align__(16) unsigned short Vl[2][64 * 64];
    __shared__ __align__(16) unsigned short Pl[4][16 * 68];  // stride 68: conflict-free writes

    const int bh    = blockIdx.y;
    const int qtile = gridDim.x - 1 - blockIdx.x;   // long blocks dispatch first
    const int qBase = qtile * 64;
    const int wave  = threadIdx.x >> 6;
    const int lane  = threadIdx.x & 63;
    const int llow  = lane & 15;
    const int quad  = lane >> 4;
    const int q0    = qBase + wave * 16;

    const _Float16*      Kp = K16 + (size_t)bh * SS * 64;
    const unsigned short* Vp = VTg + (size_t)bh * 64 * SS;

    const _Float16* Qp = Q16 + ((size_t)bh * SS + q0) * 64;
    v8h qa0 = *(const v8h*)(Qp + llow * 64 + quad * 8);
    v8h qa1 = *(const v8h*)(Qp + llow * 64 + 32 + quad * 8);

    v4f o[4];
    float lacc[4] = {0.f, 0.f, 0.f, 0.f};
#pragma unroll
    for (int nb = 0; nb < 4; nb++) o[nb] = (v4f){0.f, 0.f, 0.f, 0.f};

    const int nt = qtile + 1;

    // prefetch tile 0 into buf 0
#pragma unroll
    for (int rep = 0; rep < 2; rep++) {
        int c = rep * 256 + threadIdx.x;
        int row = c >> 3, g = (c & 7) ^ (row & 7);
        async16(Kp + (size_t)row * 64 + g * 8, &Kl[0][(rep * 256 + wave * 64) * 8]);
        async16(Vp + (size_t)row * SS + g * 8, &Vl[0][(rep * 256 + wave * 64) * 8]);
    }

    for (int t = 0; t < nt; t++) {
        __syncthreads();                 // drains this tile's DMA (vmcnt before barrier)
        if (t + 1 < nt) {                // prefetch AFTER barrier -> overlaps compute
            const int ktn = (t + 1) * 64, bufn = (t + 1) & 1;
#pragma unroll
            for (int rep = 0; rep < 2; rep++) {
                int c = rep * 256 + threadIdx.x;
                int row = c >> 3, g = (c & 7) ^ (row & 7);
                async16(Kp + (size_t)(ktn + row) * 64 + g * 8,
                        &Kl[bufn][(rep * 256 + wave * 64) * 8]);
                async16(Vp + (size_t)row * SS + ktn + g * 8,
                        &Vl[bufn][(rep * 256 + wave * 64) * 8]);
            }
        }
        const int buf = t & 1, kt = t * 64;

        // ---- QK^T ----
        v4f sc[4];
#pragma unroll
        for (int cb = 0; cb < 4; cb++) {
            const int rk = 16 * cb + llow, sw = llow & 7;
            v8h k0 = *(const v8h*)&Kl[buf][rk * 64 + ((quad ^ sw)) * 8];
            v8h k1 = *(const v8h*)&Kl[buf][rk * 64 + (((4 + quad) ^ sw)) * 8];
            v4f a = (v4f){0.f, 0.f, 0.f, 0.f};
            a = __builtin_amdgcn_mfma_f32_16x16x32_f16(qa0, k0, a, 0, 0, 0);
            a = __builtin_amdgcn_mfma_f32_16x16x32_f16(qa1, k1, a, 0, 0, 0);
            sc[cb] = a;
        }

        // ---- mask + fixed-C exp + l accum + P write (no cross-lane ops) ----
#pragma unroll
        for (int cb = 0; cb < 4; cb++) {
            const int key = kt + 16 * cb + llow;
#pragma unroll
            for (int r = 0; r < 4; r++) {
                const int row = q0 + quad * 4 + r;
                float sv = sc[cb][r];
                sv = (key <= row && sv != 0.f) ? sv : NEGV;   // faithful quirky mask
                float p = __expf(sv - CFIX);                  // masked -> exactly 0
                lacc[r] += p;
                Pl[wave][(quad * 4 + r) * 68 + 16 * cb + llow] = f2bf(p);
            }
        }

        // ---- P: C-layout -> A-layout via per-wave LDS (2x b64 reads) ----
        v8s pa0, pa1;
        {
            v4s a0 = *(const v4s*)&Pl[wave][llow * 68 + quad * 8];
            v4s a1 = *(const v4s*)&Pl[wave][llow * 68 + quad * 8 + 4];
            v4s b0 = *(const v4s*)&Pl[wave][llow * 68 + 32 + quad * 8];
            v4s b1 = *(const v4s*)&Pl[wave][llow * 68 + 32 + quad * 8 + 4];
#pragma unroll
            for (int j = 0; j < 4; j++) {
                pa0[j] = a0[j]; pa0[j + 4] = a1[j];
                pa1[j] = b0[j]; pa1[j + 4] = b1[j];
            }
        }

        // ---- PV (bf16) ----
#pragma unroll
        for (int nb = 0; nb < 4; nb++) {
            const int rv = 16 * nb + llow, sw = llow & 7;
            v8s vv0 = *(const v8s*)&Vl[buf][rv * 64 + ((quad ^ sw)) * 8];
            v8s vv1 = *(const v8s*)&Vl[buf][rv * 64 + (((4 + quad) ^ sw)) * 8];
            o[nb] = __builtin_amdgcn_mfma_f32_16x16x32_bf16(pa0, vv0, o[nb], 0, 0, 0);
            o[nb] = __builtin_amdgcn_mfma_f32_16x16x32_bf16(pa1, vv1, o[nb], 0, 0, 0);
        }
    }

    // ---- epilogue: single l reduce + O write (fp16) ----
#pragma unroll
    for (int r = 0; r < 4; r++) {
        lacc[r] += __shfl_xor(lacc[r], 1);
        lacc[r] += __shfl_xor(lacc[r], 2);
        lacc[r] += __shfl_xor(lacc[r], 4);
        lacc[r] += __shfl_xor(lacc[r], 8);
    }
    _Float16* Op = O16 + ((size_t)bh * SS + q0) * 64;
#pragma unroll
    for (int nb = 0; nb < 4; nb++)
#pragma unroll
        for (int r = 0; r < 4; r++)
            Op[(quad * 4 + r) * 64 + 16 * nb + llow] = (_Float16)(o[nb][r] / lacc[r]);
}

// ---------------------------------------------------------------------------
// Kernel 3a: Wo -> WoT fp16 [64 cols][768 k] (transpose + convert).
// ---------------------------------------------------------------------------
__global__ void prep_kernel(const float* __restrict__ Wo, _Float16* __restrict__ WoT)
{
    int e = blockIdx.x * 256 + threadIdx.x;
    if (e < 768 * 64) {
        int k = e >> 6, c = e & 63;
        WoT[c * 768 + k] = (_Float16)Wo[e];
    }
}

// ---------------------------------------------------------------------------
// Kernel 3b: output projection via MFMA. Block = 16 rows; 4 waves split K=768
// (6 kb of 32 each); LDS reduce; fp32 out.
// ---------------------------------------------------------------------------
__global__ __launch_bounds__(256) void out_kernel(
    const _Float16* __restrict__ O16, const _Float16* __restrict__ WoT,
    const float* __restrict__ bo, float* __restrict__ out)
{
    __shared__ __align__(16) float red[4][16][66];
    const int r0   = blockIdx.x * 16;
    const int wave = threadIdx.x >> 6, lane = threadIdx.x & 63;
    const int llow = lane & 15, quad = lane >> 4;
    const int b = r0 >> 11, s = r0 & 2047;          // 16 | 2048: no straddle

    v4f acc[4];
#pragma unroll
    for (int cb = 0; cb < 4; cb++) acc[cb] = (v4f){0.f, 0.f, 0.f, 0.f};

#pragma unroll
    for (int i = 0; i < 6; i++) {
        const int kb = wave * 6 + i;                // 0..23
        const int h = kb >> 1, dseg = (kb & 1) * 32;
        v8h af = *(const v8h*)(O16 + ((size_t)(b * HH + h) * SS + s + llow) * 64 + dseg + quad * 8);
#pragma unroll
        for (int cb = 0; cb < 4; cb++) {
            v8h bf = *(const v8h*)(WoT + (size_t)(16 * cb + llow) * 768 + kb * 32 + quad * 8);
            acc[cb] = __builtin_amdgcn_mfma_f32_16x16x32_f16(af, bf, acc[cb], 0, 0, 0);
        }
    }

#pragma unroll
    for (int cb = 0; cb < 4; cb++)
#pragma unroll
        for (int r = 0; r < 4; r++)
            red[wave][quad * 4 + r][16 * cb + llow] = acc[cb][r];
    __syncthreads();

    const int col = threadIdx.x & 63, rr = threadIdx.x >> 6;
    const float bias = bo[col];
    for (int i = rr; i < 16; i += 4) {
        float sum = red[0][i][col] + red[1][i][col] + red[2][i][col] + red[3][i][col] + bias;
        out[(size_t)(r0 + i) * 64 + col] = sum;
    }
}

// ---------------------------------------------------------------------------
extern "C" void kernel_launch(void* const* d_in, const int* in_sizes, int n_in,
                              void* d_out, int out_size, void* d_ws, size_t ws_size,
                              hipStream_t stream)
{
    const float* x  = (const float*)d_in[0];
    const float* Wq = (const float*)d_in[1];
    const float* bq = (const float*)d_in[2];
    const float* Wk = (const float*)d_in[3];
    const float* bk = (const float*)d_in[4];
    const float* Wv = (const float*)d_in[5];
    const float* bv = (const float*)d_in[6];
    const float* Wo = (const float*)d_in[7];
    const float* bo = (const float*)d_in[8];
    float* out = (float*)d_out;

    char* w = (char*)d_ws;
    const size_t MB6 = (size_t)BB * HH * SS * DD * 2;   // 6 MB per tensor
    _Float16*       Q16 = (_Float16*)(w);
    _Float16*       K16 = (_Float16*)(w + MB6);
    unsigned short* VT  = (unsigned short*)(w + 2 * MB6);
    _Float16*       O16 = (_Float16*)(w + 3 * MB6);
    _Float16*       WoT = (_Float16*)(w + 4 * MB6);

    prep_kernel<<<192, 256, 0, stream>>>(Wo, WoT);
    qkv_kernel<<<dim3(256, 9), 256, 0, stream>>>(x, Wq, bq, Wk, bk, Wv, bv, Q16, K16, VT);
    attn_kernel<<<dim3(SS / 64, BB * HH), 256, 0, stream>>>(Q16, K16, VT, O16);
    out_kernel<<<(BB * SS) / 16, 256, 0, stream>>>(O16, WoT, bo, out);
}